// Round 1
// baseline (188.000 us; speedup 1.0000x reference)
//
#include <hip/hip_runtime.h>
#include <hip/hip_bf16.h>

// Expand: repeat each x[b,i,:] dims[b,i] times along axis 1, left-packed,
// zero-padded to T = max_b sum(dims[b,:]).
// Shapes fixed by setup_inputs(): B=16, S=1024, D=384 (D derived at launch).

#define S_TOKENS 1024
#define B_BATCH 16

// --- Kernel 1: per-batch inclusive prefix sum of dims (Hillis-Steele in LDS) ---
__global__ void scan_kernel(const int* __restrict__ dims, int* __restrict__ csum) {
    __shared__ int buf[S_TOKENS];
    const int b = blockIdx.x;
    const int tid = threadIdx.x;
    buf[tid] = dims[b * S_TOKENS + tid];
    __syncthreads();
#pragma unroll
    for (int off = 1; off < S_TOKENS; off <<= 1) {
        int add = (tid >= off) ? buf[tid - off] : 0;
        __syncthreads();
        buf[tid] += add;
        __syncthreads();
    }
    csum[b * S_TOKENS + tid] = buf[tid];
}

// --- Kernel 2: one thread per float4 of output; binary search + gather ---
// k -> row = k/96 (96 = D/4 float4 per row), row -> (b, t).
// src token = first i with csum[b][i] > t  (searchsorted 'right').
__global__ void expand_kernel(const float4* __restrict__ x4,
                              const int* __restrict__ csum,
                              float4* __restrict__ out4,
                              int T, int Q /* = D/4 */, int n4) {
    int k = blockIdx.x * blockDim.x + threadIdx.x;
    if (k >= n4) return;

    int row = k / Q;          // Q is 96 at runtime; uniform per launch
    int q   = k - row * Q;
    int b   = row / T;
    int t   = row - b * T;

    const int* __restrict__ c = csum + b * S_TOKENS;
    int total = c[S_TOKENS - 1];

    float4 val = make_float4(0.f, 0.f, 0.f, 0.f);
    if (t < total) {
        // lower bound of (> t): answer in [0, S-1] since c[S-1] = total > t
        int lo = 0, hi = S_TOKENS - 1;
        while (lo < hi) {
            int mid = (lo + hi) >> 1;
            if (c[mid] > t) hi = mid;
            else            lo = mid + 1;
        }
        val = x4[(b * S_TOKENS + lo) * Q + q];
    }
    out4[k] = val;
}

extern "C" void kernel_launch(void* const* d_in, const int* in_sizes, int n_in,
                              void* d_out, int out_size, void* d_ws, size_t ws_size,
                              hipStream_t stream) {
    const float* x      = (const float*)d_in[0];   // [B, S, D] fp32
    const int*   dims   = (const int*)d_in[1];     // [B, S] int32
    float*       out    = (float*)d_out;           // [B, T, D] fp32

    const int D = in_sizes[0] / in_sizes[1];       // 384
    const int Q = D / 4;                           // 96
    const int T = out_size / (B_BATCH * D);        // max total length

    int* csum = (int*)d_ws;                        // B*S ints = 64 KB

    scan_kernel<<<B_BATCH, S_TOKENS, 0, stream>>>(dims, csum);

    const int n4 = out_size / 4;
    const int block = 256;
    const int grid = (n4 + block - 1) / block;
    expand_kernel<<<grid, block, 0, stream>>>((const float4*)x, csum,
                                              (float4*)out, T, Q, n4);
}

// Round 3
// 149.418 us; speedup vs baseline: 1.2582x; 1.2582x over previous
//
#include <hip/hip_runtime.h>
#include <hip/hip_bf16.h>

// Expand: repeat each x[b,i,:] dimensions[b,i] times along axis 1, left-packed,
// zero-padded to T = max_b sum(dims[b,:]).
// Shapes fixed by setup_inputs(): B=16, S=1024, D=384.

#define S_TOKENS 1024
#define B_BATCH 16
#define QVEC 96   // D/4 float4 per row (D=384)

// --- Kernel 1: per-batch scan of dims + scatter row->src map ---
// idx[b*T + t] = absolute source row (b*S + i) for output position t, or -1 pad.
__global__ void prep_kernel(const int* __restrict__ dims, int* __restrict__ idx,
                            int T) {
    __shared__ int buf[S_TOKENS];
    const int b = blockIdx.x;
    const int tid = threadIdx.x;
    buf[tid] = dims[b * S_TOKENS + tid];
    __syncthreads();
#pragma unroll
    for (int off = 1; off < S_TOKENS; off <<= 1) {
        int add = (tid >= off) ? buf[tid - off] : 0;
        __syncthreads();
        buf[tid] += add;
        __syncthreads();
    }
    // inclusive csum now in buf
    const int total = buf[S_TOKENS - 1];          // broadcast read
    const int end   = buf[tid];
    const int start = (tid == 0) ? 0 : buf[tid - 1];
    int* __restrict__ idx_b = idx + b * T;
    const int src = b * S_TOKENS + tid;
    for (int t = start; t < end; ++t) idx_b[t] = src;          // <=9 writes/thread
    for (int t = total + tid; t < T; t += S_TOKENS) idx_b[t] = -1;  // pad tail
}

// --- Kernel 2: one thread per float4 of output; map lookup + gather ---
__global__ void expand_kernel(const float4* __restrict__ x4,
                              const int* __restrict__ idx,
                              float4* __restrict__ out4,
                              int n4) {
    int k = blockIdx.x * blockDim.x + threadIdx.x;
    if (k >= n4) return;
    int row = k / QVEC;            // compile-time magic-mul
    int q   = k - row * QVEC;
    int src = idx[row];            // 96 consecutive threads share -> L1 broadcast
    float4 val = make_float4(0.f, 0.f, 0.f, 0.f);
    if (src >= 0) val = x4[src * QVEC + q];
    out4[k] = val;
}

extern "C" void kernel_launch(void* const* d_in, const int* in_sizes, int n_in,
                              void* d_out, int out_size, void* d_ws, size_t ws_size,
                              hipStream_t stream) {
    const float* x    = (const float*)d_in[0];   // [B, S, D] fp32
    const int*   dims = (const int*)d_in[1];     // [B, S] int32
    float*       out  = (float*)d_out;           // [B, T, D] fp32

    const int D = in_sizes[0] / in_sizes[1];     // 384
    const int T = out_size / (B_BATCH * D);      // max total length (~4800)

    int* idx = (int*)d_ws;                       // B*T ints (~320 KB) in workspace

    prep_kernel<<<B_BATCH, S_TOKENS, 0, stream>>>(dims, idx, T);

    const int n4 = out_size / 4;
    const int block = 256;
    const int grid = (n4 + block - 1) / block;
    expand_kernel<<<grid, block, 0, stream>>>((const float4*)x, idx,
                                              (float4*)out, n4);
}